// Round 1
// baseline (2011.973 us; speedup 1.0000x reference)
//
#include <hip/hip_runtime.h>
#include <cstdint>

#define POOLK 7
#define NCLS 91
#define FH 50
#define FW 50
#define FCH 256
#define DIM (FCH * POOLK * POOLK) /* 12544 */
#define HID 1024
#define TOPK_OUT 100
#define DW_MAXF 4.135166556742356f

// ---------------------------------------------------------------- ROI pool
__global__ __launch_bounds__(256) void roi_pool_kernel(
    const float* __restrict__ feat, const float* __restrict__ props,
    float* __restrict__ pooled, int n0, int rows,
    const int* __restrict__ img_h, const int* __restrict__ img_w)
{
    int tid = blockIdx.x * 256 + threadIdx.x;
    int total = rows * DIM;
    if (tid >= total) return;
    int cell = tid % 49;
    int c    = (tid / 49) % FCH;
    int rl   = tid / DIM;
    int py = cell / 7, px = cell % 7;
    int n = n0 + rl;

    float scale = (float)fmin((double)FH / (double)img_h[0],
                              (double)FW / (double)img_w[0]);
    float x1 = rintf(props[n * 4 + 0] * scale);
    float y1 = rintf(props[n * 4 + 1] * scale);
    float x2 = rintf(props[n * 4 + 2] * scale);
    float y2 = rintf(props[n * 4 + 3] * scale);
    float roiw = fmaxf(x2 - x1 + 1.f, 1.f);
    float roih = fmaxf(y2 - y1 + 1.f, 1.f);

    float hsf = fminf(fmaxf(floorf((float)py * roih / 7.f) + y1, 0.f), (float)FH);
    float hef = fminf(fmaxf(ceilf(((float)py + 1.f) * roih / 7.f) + y1, 0.f), (float)FH);
    float wsf = fminf(fmaxf(floorf((float)px * roiw / 7.f) + x1, 0.f), (float)FW);
    float wef = fminf(fmaxf(ceilf(((float)px + 1.f) * roiw / 7.f) + x1, 0.f), (float)FW);
    int h0 = (int)hsf, h1 = (int)hef, w0 = (int)wsf, w1 = (int)wef;

    float m = 0.f;
    if (h0 < h1 && w0 < w1) {
        m = -INFINITY;
        const float* fp = feat + (size_t)c * (FH * FW);
        for (int h = h0; h < h1; ++h) {
            const float* rowp = fp + h * FW;
            for (int w = w0; w < w1; ++w) m = fmaxf(m, rowp[w]);
        }
    }
    pooled[(size_t)rl * DIM + c * 49 + cell] = m;
}

// ------------------------------------------------- GEMM  C = A * W^T + b
// A: M x K row-major, W: N x K row-major (both K-major -> coalesced loads)
#define BM 64
#define BN 64
#define BK 32
#define LDP 68
__global__ __launch_bounds__(256) void gemm_nt_bias(
    const float* __restrict__ A, const float* __restrict__ W,
    const float* __restrict__ bias, float* __restrict__ C,
    int M, int N, int K, int relu)
{
    __shared__ float As[BK * LDP];
    __shared__ float Bs[BK * LDP];
    int t = threadIdx.x;
    int m0 = blockIdx.y * BM, n0 = blockIdx.x * BN;
    int tm = t >> 4, tn = t & 15;   // 16x16 threads of 4x4 micro-tiles
    float acc[4][4] = {};

    for (int k0 = 0; k0 < K; k0 += BK) {
        #pragma unroll
        for (int r = 0; r < 2; ++r) {
            int fi = t + r * 256;          // 0..511 float4 slots
            int row = fi >> 3;             // 0..63
            int c4  = (fi & 7) * 4;        // 0..28
            float4 av = make_float4(0, 0, 0, 0), bv = make_float4(0, 0, 0, 0);
            int gm = m0 + row, gn = n0 + row;
            if (gm < M) av = *(const float4*)(A + (size_t)gm * K + k0 + c4);
            if (gn < N) bv = *(const float4*)(W + (size_t)gn * K + k0 + c4);
            #pragma unroll
            for (int j = 0; j < 4; ++j) {
                As[(c4 + j) * LDP + row] = ((const float*)&av)[j];
                Bs[(c4 + j) * LDP + row] = ((const float*)&bv)[j];
            }
        }
        __syncthreads();
        #pragma unroll
        for (int kk = 0; kk < BK; ++kk) {
            float4 a = *(const float4*)&As[kk * LDP + tm * 4];
            float4 b = *(const float4*)&Bs[kk * LDP + tn * 4];
            const float* ap = (const float*)&a;
            const float* bp = (const float*)&b;
            #pragma unroll
            for (int i = 0; i < 4; ++i)
                #pragma unroll
                for (int j = 0; j < 4; ++j)
                    acc[i][j] = fmaf(ap[i], bp[j], acc[i][j]);
        }
        __syncthreads();
    }
    #pragma unroll
    for (int i = 0; i < 4; ++i) {
        int gm = m0 + tm * 4 + i;
        if (gm >= M) continue;
        #pragma unroll
        for (int j = 0; j < 4; ++j) {
            int gn = n0 + tn * 4 + j;
            if (gn >= N) continue;
            float v = acc[i][j] + bias[gn];
            if (relu) v = fmaxf(v, 0.f);
            C[(size_t)gm * N + gn] = v;
        }
    }
}

// ------------------------------------- per-row softmax/argmax + reg + decode
__global__ __launch_bounds__(256) void decode_kernel(
    const float* __restrict__ cls, const float* __restrict__ x2buf,
    const float* __restrict__ reg_w, const float* __restrict__ reg_b,
    const float* __restrict__ props,
    float* __restrict__ scores, int* __restrict__ labels,
    float* __restrict__ boxes, int* __restrict__ valid,
    unsigned int* __restrict__ gmax,
    int n0, int rows, const int* __restrict__ img_h, const int* __restrict__ img_w)
{
    int wid = threadIdx.x >> 6, lane = threadIdx.x & 63;
    int rl = blockIdx.x * 4 + wid;
    if (rl >= rows) return;
    int r = n0 + rl;

    float v0 = (lane < NCLS) ? cls[(size_t)r * NCLS + lane] : -INFINITY;
    float v1 = (lane + 64 < NCLS) ? cls[(size_t)r * NCLS + lane + 64] : -INFINITY;

    float mall = fmaxf(v0, v1);
    for (int s = 32; s; s >>= 1) mall = fmaxf(mall, __shfl_xor(mall, s));

    // fg argmax (classes 1..90), first-index tie-break
    float bv = -INFINITY; int bi = 1 << 30;
    if (lane >= 1 && lane < NCLS) { bv = v0; bi = lane; }
    if (lane + 64 < NCLS && v1 > bv) { bv = v1; bi = lane + 64; }
    for (int s = 32; s; s >>= 1) {
        float ov = __shfl_xor(bv, s); int oi = __shfl_xor(bi, s);
        if (ov > bv || (ov == bv && oi < bi)) { bv = ov; bi = oi; }
    }

    float den = ((lane < NCLS) ? expf(v0 - mall) : 0.f) +
                ((lane + 64 < NCLS) ? expf(v1 - mall) : 0.f);
    for (int s = 32; s; s >>= 1) den += __shfl_xor(den, s);

    float score = expf(bv - mall) / den;
    int label = bi;

    // selected reg row: 4 dot products of length 1024
    float dsum[4];
    const float* xr = x2buf + (size_t)rl * HID;
    #pragma unroll
    for (int d = 0; d < 4; ++d) {
        const float* wr = reg_w + (size_t)(label * 4 + d) * HID;
        float s = 0.f;
        for (int k = lane; k < HID; k += 64) s = fmaf(xr[k], wr[k], s);
        for (int sh = 32; sh; sh >>= 1) s += __shfl_xor(s, sh);
        dsum[d] = s + reg_b[label * 4 + d];
    }

    if (lane == 0) {
        float p0 = props[r * 4 + 0], p1 = props[r * 4 + 1];
        float p2 = props[r * 4 + 2], p3 = props[r * 4 + 3];
        float pw = p2 - p0, ph = p3 - p1;
        float pcx = p0 + 0.5f * pw, pcy = p1 + 0.5f * ph;
        float dx = dsum[0], dy = dsum[1];
        float dw = fminf(dsum[2], DW_MAXF), dh = fminf(dsum[3], DW_MAXF);
        float cx = dx * pw + pcx, cy = dy * ph + pcy;
        float bw = expf(dw) * pw, bh = expf(dh) * ph;
        float iw = (float)img_w[0], ih = (float)img_h[0];
        float b0 = fminf(fmaxf(cx - 0.5f * bw, 0.f), iw);
        float b1 = fminf(fmaxf(cy - 0.5f * bh, 0.f), ih);
        float b2 = fminf(fmaxf(cx + 0.5f * bw, 0.f), iw);
        float b3 = fminf(fmaxf(cy + 0.5f * bh, 0.f), ih);
        boxes[r * 4 + 0] = b0; boxes[r * 4 + 1] = b1;
        boxes[r * 4 + 2] = b2; boxes[r * 4 + 3] = b3;
        scores[r] = score; labels[r] = label;
        valid[r] = (score >= 0.05f) && (b2 - b0 >= 1.f) && (b3 - b1 >= 1.f);
        atomicMax(gmax, __float_as_uint(b0)); atomicMax(gmax, __float_as_uint(b1));
        atomicMax(gmax, __float_as_uint(b2)); atomicMax(gmax, __float_as_uint(b3));
    }
}

// ---------------------------------------- stable argsort via O(N^2) ranking
__global__ __launch_bounds__(256) void rank_kernel(
    const float* __restrict__ scores, const int* __restrict__ valid,
    int* __restrict__ order, int N)
{
    int i = blockIdx.x * 256 + threadIdx.x;
    __shared__ float sk[256];
    float ki = INFINITY;
    if (i < N && valid[i]) ki = -scores[i];
    int rank = 0;
    for (int j0 = 0; j0 < N; j0 += 256) {
        int j = j0 + threadIdx.x;
        float kj = INFINITY;
        if (j < N && valid[j]) kj = -scores[j];
        __syncthreads();
        sk[threadIdx.x] = kj;
        __syncthreads();
        int lim = min(256, N - j0);
        for (int jj = 0; jj < lim; ++jj) {
            float k2 = sk[jj];
            int jidx = j0 + jj;
            rank += (k2 < ki) || (k2 == ki && jidx < i);
        }
    }
    if (i < N) order[rank] = i;
}

// --------------------------------- gather sorted arrays + offset boxes + vbits
__global__ __launch_bounds__(256) void sortprep_kernel(
    const int* __restrict__ order, const float* __restrict__ boxes,
    const float* __restrict__ scores, const int* __restrict__ labels,
    const int* __restrict__ valid, const unsigned int* __restrict__ gmax,
    float* __restrict__ sob, float* __restrict__ sarea,
    float* __restrict__ sraw, float* __restrict__ ssc, int* __restrict__ slb,
    unsigned long long* __restrict__ vbits, int N)
{
    int i = blockIdx.x * 256 + threadIdx.x;
    if (i >= N) return;
    int oi = order[i];
    float off = (float)labels[oi] * (__uint_as_float(gmax[0]) + 1.0f);
    float b0 = boxes[oi * 4 + 0] + off, b1 = boxes[oi * 4 + 1] + off;
    float b2 = boxes[oi * 4 + 2] + off, b3 = boxes[oi * 4 + 3] + off;
    sob[i * 4 + 0] = b0; sob[i * 4 + 1] = b1; sob[i * 4 + 2] = b2; sob[i * 4 + 3] = b3;
    sarea[i] = (b2 - b0) * (b3 - b1);
    sraw[i * 4 + 0] = boxes[oi * 4 + 0]; sraw[i * 4 + 1] = boxes[oi * 4 + 1];
    sraw[i * 4 + 2] = boxes[oi * 4 + 2]; sraw[i * 4 + 3] = boxes[oi * 4 + 3];
    ssc[i] = scores[oi]; slb[i] = labels[oi];
    if (valid[oi]) atomicOr(&vbits[i >> 6], 1ull << (i & 63));
}

// ----------------------------------------------- IoU>thresh bitmask (j > i)
__global__ __launch_bounds__(256) void mask_kernel(
    const float* __restrict__ sob, const float* __restrict__ sarea,
    unsigned long long* __restrict__ mask, int N, int NW)
{
    int t = threadIdx.x;
    int w = t & 31, il = t >> 5;
    int i = blockIdx.x * 8 + il;
    if (i >= N || w >= NW) return;
    float4 bi = *(const float4*)(sob + (size_t)i * 4);
    float ai = sarea[i];
    unsigned long long bits = 0;
    int jbase = w * 64;
    for (int b = 0; b < 64; ++b) {
        int j = jbase + b;
        if (j > i && j < N) {
            float4 bj = *(const float4*)(sob + (size_t)j * 4);
            float xl = fmaxf(bi.x, bj.x), yt = fmaxf(bi.y, bj.y);
            float xr = fminf(bi.z, bj.z), yb = fminf(bi.w, bj.w);
            float inter = fmaxf(xr - xl, 0.f) * fmaxf(yb - yt, 0.f);
            float iou = inter / (ai + sarea[j] - inter + 1e-9f);
            if (iou > 0.5f) bits |= 1ull << b;
        }
    }
    mask[(size_t)i * NW + w] = bits;
}

// ------------------------------------------------ serial NMS scan + outputs
__global__ __launch_bounds__(64) void nms_kernel(
    const unsigned long long* __restrict__ mask,
    const unsigned long long* __restrict__ vbits,
    const float* __restrict__ sraw, const float* __restrict__ ssc,
    const int* __restrict__ slb, float* __restrict__ out, int N, int NW)
{
    __shared__ unsigned long long sm[128][32];
    int lane = threadIdx.x;
    unsigned long long supp = 0;
    unsigned long long vw = (lane < NW) ? vbits[lane] : 0ull;
    int cnt = 0;
    for (int base = 0; base < N; base += 128) {
        int rows = min(128, N - base);
        for (int idx = lane; idx < rows * NW; idx += 64)
            sm[idx / NW][idx % NW] = mask[(size_t)(base + idx / NW) * NW + idx % NW];
        __syncthreads();
        for (int ii = 0; ii < rows; ++ii) {
            int i = base + ii;
            int w = i >> 6, b = i & 63;
            unsigned long long sw = __shfl(supp, w);
            unsigned long long vv = __shfl(vw, w);
            bool keep = ((vv >> b) & 1ull) && !((sw >> b) & 1ull);
            if (keep) {
                if (lane < NW) supp |= sm[ii][lane];
                if (cnt < TOPK_OUT) {
                    if (lane < 4) out[cnt * 4 + lane] = sraw[i * 4 + lane];
                    if (lane == 4) out[4 * TOPK_OUT + cnt] = (float)slb[i];
                    if (lane == 5) out[5 * TOPK_OUT + cnt] = ssc[i];
                }
                cnt++;
            }
        }
        __syncthreads();
    }
    for (int s = cnt; s < TOPK_OUT; ++s) {
        if (lane < 4) out[s * 4 + lane] = 0.f;
        if (lane == 4) out[4 * TOPK_OUT + s] = 0.f;
        if (lane == 5) out[5 * TOPK_OUT + s] = 0.f;
    }
}

// --------------------------------------------------------------------------
extern "C" void kernel_launch(void* const* d_in, const int* in_sizes, int n_in,
                              void* d_out, int out_size, void* d_ws, size_t ws_size,
                              hipStream_t stream)
{
    const float* feat  = (const float*)d_in[0];
    const float* props = (const float*)d_in[1];
    const float* fc1_w = (const float*)d_in[2];
    const float* fc1_b = (const float*)d_in[3];
    const float* fc2_w = (const float*)d_in[4];
    const float* fc2_b = (const float*)d_in[5];
    const float* cls_w = (const float*)d_in[6];
    const float* cls_b = (const float*)d_in[7];
    const float* reg_w = (const float*)d_in[8];
    const float* reg_b = (const float*)d_in[9];
    const int* img_h = (const int*)d_in[10];
    const int* img_w = (const int*)d_in[11];
    float* out = (float*)d_out;

    int N = in_sizes[1] / 4;          // 2000
    int NW = (N + 63) >> 6;           // 32

    auto al = [](size_t x) { return (x + 255) & ~(size_t)255; };
    size_t fixedBytes =
        al((size_t)N * NCLS * 4) + al((size_t)N * 4) + al((size_t)N * 4) +
        al((size_t)N * 4) + al((size_t)N * 16) + al((size_t)N * 4) +
        al((size_t)N * 16) + al((size_t)N * 4) + al((size_t)N * 16) +
        al((size_t)N * 4) + al((size_t)N * 4) + al((size_t)NW * 8) + al(4) +
        al((size_t)N * NW * 8);

    int chunk = N;
    while (chunk > 128 &&
           fixedBytes + al((size_t)chunk * DIM * 4) + 2 * al((size_t)chunk * HID * 4) > ws_size)
        chunk = (chunk + 1) / 2;

    char* p = (char*)d_ws;
    auto grab = [&](size_t bytes) { char* q = p; p += al(bytes); return q; };
    float* pooled = (float*)grab((size_t)chunk * DIM * 4);
    float* x1buf  = (float*)grab((size_t)chunk * HID * 4);
    float* x2buf  = (float*)grab((size_t)chunk * HID * 4);
    float* cls    = (float*)grab((size_t)N * NCLS * 4);
    float* scores = (float*)grab((size_t)N * 4);
    int*   labels = (int*)grab((size_t)N * 4);
    int*   valid  = (int*)grab((size_t)N * 4);
    float* boxes  = (float*)grab((size_t)N * 16);
    int*   order  = (int*)grab((size_t)N * 4);
    float* sob    = (float*)grab((size_t)N * 16);
    float* sarea  = (float*)grab((size_t)N * 4);
    float* sraw   = (float*)grab((size_t)N * 16);
    float* ssc    = (float*)grab((size_t)N * 4);
    int*   slb    = (int*)grab((size_t)N * 4);
    unsigned long long* vbits = (unsigned long long*)grab((size_t)NW * 8);
    unsigned int* gmax = (unsigned int*)grab(4);
    unsigned long long* maskp = (unsigned long long*)grab((size_t)N * NW * 8);

    hipMemsetAsync(vbits, 0, (size_t)NW * 8, stream);
    hipMemsetAsync(gmax, 0, 4, stream);

    for (int n0 = 0; n0 < N; n0 += chunk) {
        int rows = min(chunk, N - n0);
        {
            int total = rows * DIM;
            roi_pool_kernel<<<(total + 255) / 256, 256, 0, stream>>>(
                feat, props, pooled, n0, rows, img_h, img_w);
        }
        {
            dim3 g((HID + BN - 1) / BN, (rows + BM - 1) / BM);
            gemm_nt_bias<<<g, 256, 0, stream>>>(pooled, fc1_w, fc1_b, x1buf,
                                                rows, HID, DIM, 1);
        }
        {
            dim3 g((HID + BN - 1) / BN, (rows + BM - 1) / BM);
            gemm_nt_bias<<<g, 256, 0, stream>>>(x1buf, fc2_w, fc2_b, x2buf,
                                                rows, HID, HID, 1);
        }
        {
            dim3 g((NCLS + BN - 1) / BN, (rows + BM - 1) / BM);
            gemm_nt_bias<<<g, 256, 0, stream>>>(x2buf, cls_w, cls_b,
                                                cls + (size_t)n0 * NCLS,
                                                rows, NCLS, HID, 0);
        }
        decode_kernel<<<(rows + 3) / 4, 256, 0, stream>>>(
            cls, x2buf, reg_w, reg_b, props, scores, labels, boxes, valid,
            gmax, n0, rows, img_h, img_w);
    }

    rank_kernel<<<(N + 255) / 256, 256, 0, stream>>>(scores, valid, order, N);
    sortprep_kernel<<<(N + 255) / 256, 256, 0, stream>>>(
        order, boxes, scores, labels, valid, gmax, sob, sarea, sraw, ssc, slb,
        vbits, N);
    mask_kernel<<<(N + 7) / 8, 256, 0, stream>>>(sob, sarea, maskp, N, NW);
    nms_kernel<<<1, 64, 0, stream>>>(maskp, vbits, sraw, ssc, slb, out, N, NW);
}

// Round 2
// 1896.275 us; speedup vs baseline: 1.0610x; 1.0610x over previous
//
#include <hip/hip_runtime.h>
#include <cstdint>

#define POOLK 7
#define NCLS 91
#define FH 50
#define FW 50
#define FCH 256
#define DIM (FCH * POOLK * POOLK) /* 12544 */
#define HID 1024
#define TOPK_OUT 100
#define DW_MAXF 4.135166556742356f

typedef __attribute__((ext_vector_type(8))) short short8;
typedef __attribute__((ext_vector_type(4))) float f32x4;

// ---------------------------------------------------------------- ROI pool
__global__ __launch_bounds__(256) void roi_pool_kernel(
    const float* __restrict__ feat, const float* __restrict__ props,
    float* __restrict__ pooled, int n0, int rows,
    const int* __restrict__ img_h, const int* __restrict__ img_w)
{
    int tid = blockIdx.x * 256 + threadIdx.x;
    int total = rows * DIM;
    if (tid >= total) return;
    int cell = tid % 49;
    int c    = (tid / 49) % FCH;
    int rl   = tid / DIM;
    int py = cell / 7, px = cell % 7;
    int n = n0 + rl;

    float scale = (float)fmin((double)FH / (double)img_h[0],
                              (double)FW / (double)img_w[0]);
    float x1 = rintf(props[n * 4 + 0] * scale);
    float y1 = rintf(props[n * 4 + 1] * scale);
    float x2 = rintf(props[n * 4 + 2] * scale);
    float y2 = rintf(props[n * 4 + 3] * scale);
    float roiw = fmaxf(x2 - x1 + 1.f, 1.f);
    float roih = fmaxf(y2 - y1 + 1.f, 1.f);

    float hsf = fminf(fmaxf(floorf((float)py * roih / 7.f) + y1, 0.f), (float)FH);
    float hef = fminf(fmaxf(ceilf(((float)py + 1.f) * roih / 7.f) + y1, 0.f), (float)FH);
    float wsf = fminf(fmaxf(floorf((float)px * roiw / 7.f) + x1, 0.f), (float)FW);
    float wef = fminf(fmaxf(ceilf(((float)px + 1.f) * roiw / 7.f) + x1, 0.f), (float)FW);
    int h0 = (int)hsf, h1 = (int)hef, w0 = (int)wsf, w1 = (int)wef;

    float m = 0.f;
    if (h0 < h1 && w0 < w1) {
        m = -INFINITY;
        const float* fp = feat + (size_t)c * (FH * FW);
        for (int h = h0; h < h1; ++h) {
            const float* rowp = fp + h * FW;
            for (int w = w0; w < w1; ++w) m = fmaxf(m, rowp[w]);
        }
    }
    pooled[(size_t)rl * DIM + c * 49 + cell] = m;
}

// ---------------------------------------------------------------- fp32 -> bf16 hi/lo
__device__ __forceinline__ void split2(float x, unsigned short& h, unsigned short& l)
{
    unsigned u = __float_as_uint(x);
    unsigned r = u + 0x7FFFu + ((u >> 16) & 1u);
    h = (unsigned short)(r >> 16);
    float hf = __uint_as_float(r & 0xFFFF0000u);
    float lof = x - hf;
    unsigned ul = __float_as_uint(lof);
    unsigned rl2 = ul + 0x7FFFu + ((ul >> 16) & 1u);
    l = (unsigned short)(rl2 >> 16);
}

// ------------------------------------------------- split-K MFMA bf16x3 GEMM
//   part[s][m][n] += A[m][:] . W[n][:]   over this split's K-range
//   A: M x K fp32 row-major, W: N x K fp32 row-major
#define GBM 128
#define GBN 128
#define GBK 32
#define LDS_STRIDE 40   /* shorts per row: 80B, 16B-aligned, conflict-light */
__global__ __launch_bounds__(256, 2) void gemm3_kernel(
    const float* __restrict__ A, const float* __restrict__ W,
    float* __restrict__ part, int M, int N, int K, int ksteps, int KS)
{
    __shared__ short Ah[GBM * LDS_STRIDE];
    __shared__ short Al[GBM * LDS_STRIDE];
    __shared__ short Bh[GBN * LDS_STRIDE];
    __shared__ short Bl[GBN * LDS_STRIDE];

    int t = threadIdx.x;
    int m0 = blockIdx.y * GBM, n0 = blockIdx.x * GBN;
    int steps_per = (ksteps + KS - 1) / KS;
    int ks0 = blockIdx.z * steps_per;
    int ks1 = min(ksteps, ks0 + steps_per);

    int lane = t & 63, wave = t >> 6;
    int wr = wave >> 1, wc = wave & 1;      // 2x2 waves over 128x128, 64x64 each
    int fr = lane & 15, fg = lane >> 4;

    f32x4 acc[4][4] = {};

    for (int kt = ks0; kt < ks1; ++kt) {
        int k0 = kt * GBK;
        // ---- stage A and B tiles (fp32 -> hi/lo bf16 in LDS)
        #pragma unroll
        for (int i = 0; i < 4; ++i) {
            int f = t + 256 * i;            // 0..1023 float4 slots
            int row = f >> 3;
            int c4  = (f & 7) << 2;
            // A side
            {
                int gm = m0 + row;
                float4 v = make_float4(0.f, 0.f, 0.f, 0.f);
                if (gm < M) v = *(const float4*)(A + (size_t)gm * K + k0 + c4);
                unsigned short h[4], l[4];
                split2(v.x, h[0], l[0]); split2(v.y, h[1], l[1]);
                split2(v.z, h[2], l[2]); split2(v.w, h[3], l[3]);
                unsigned h01 = (unsigned)h[0] | ((unsigned)h[1] << 16);
                unsigned h23 = (unsigned)h[2] | ((unsigned)h[3] << 16);
                unsigned l01 = (unsigned)l[0] | ((unsigned)l[1] << 16);
                unsigned l23 = (unsigned)l[2] | ((unsigned)l[3] << 16);
                *(uint2*)&Ah[row * LDS_STRIDE + c4] = make_uint2(h01, h23);
                *(uint2*)&Al[row * LDS_STRIDE + c4] = make_uint2(l01, l23);
            }
            // B side
            {
                int gn = n0 + row;
                float4 v = make_float4(0.f, 0.f, 0.f, 0.f);
                if (gn < N) v = *(const float4*)(W + (size_t)gn * K + k0 + c4);
                unsigned short h[4], l[4];
                split2(v.x, h[0], l[0]); split2(v.y, h[1], l[1]);
                split2(v.z, h[2], l[2]); split2(v.w, h[3], l[3]);
                unsigned h01 = (unsigned)h[0] | ((unsigned)h[1] << 16);
                unsigned h23 = (unsigned)h[2] | ((unsigned)h[3] << 16);
                unsigned l01 = (unsigned)l[0] | ((unsigned)l[1] << 16);
                unsigned l23 = (unsigned)l[2] | ((unsigned)l[3] << 16);
                *(uint2*)&Bh[row * LDS_STRIDE + c4] = make_uint2(h01, h23);
                *(uint2*)&Bl[row * LDS_STRIDE + c4] = make_uint2(l01, l23);
            }
        }
        __syncthreads();
        // ---- fragments + MFMA
        short8 ah[4], al[4], bh[4], bl[4];
        #pragma unroll
        for (int mi = 0; mi < 4; ++mi) {
            int r = (wr * 64 + mi * 16 + fr) * LDS_STRIDE + fg * 8;
            ah[mi] = *(const short8*)&Ah[r];
            al[mi] = *(const short8*)&Al[r];
        }
        #pragma unroll
        for (int ni = 0; ni < 4; ++ni) {
            int r = (wc * 64 + ni * 16 + fr) * LDS_STRIDE + fg * 8;
            bh[ni] = *(const short8*)&Bh[r];
            bl[ni] = *(const short8*)&Bl[r];
        }
        #pragma unroll
        for (int mi = 0; mi < 4; ++mi)
            #pragma unroll
            for (int ni = 0; ni < 4; ++ni) {
                acc[mi][ni] = __builtin_amdgcn_mfma_f32_16x16x32_bf16(
                    ah[mi], bh[ni], acc[mi][ni], 0, 0, 0);
                acc[mi][ni] = __builtin_amdgcn_mfma_f32_16x16x32_bf16(
                    ah[mi], bl[ni], acc[mi][ni], 0, 0, 0);
                acc[mi][ni] = __builtin_amdgcn_mfma_f32_16x16x32_bf16(
                    al[mi], bh[ni], acc[mi][ni], 0, 0, 0);
            }
        __syncthreads();
    }

    // ---- store partials: C row = (lane>>4)*4 + reg, col = lane&15 (m89-verified)
    float* pbase = part + (size_t)blockIdx.z * M * N;
    #pragma unroll
    for (int mi = 0; mi < 4; ++mi) {
        #pragma unroll
        for (int ni = 0; ni < 4; ++ni) {
            int col = n0 + wc * 64 + ni * 16 + fr;
            if (col >= N) continue;
            #pragma unroll
            for (int j = 0; j < 4; ++j) {
                int row = m0 + wr * 64 + mi * 16 + fg * 4 + j;
                if (row < M) pbase[(size_t)row * N + col] = acc[mi][ni][j];
            }
        }
    }
}

// ---------------------------------------------- split-K reduce + bias (+relu)
__global__ __launch_bounds__(256) void reduce_kernel(
    const float* __restrict__ part, const float* __restrict__ bias,
    float* __restrict__ out, int M, int N, int KS, int relu)
{
    int idx = blockIdx.x * 256 + threadIdx.x;
    int tot = M * N;
    if (idx >= tot) return;
    int n = idx % N;
    float s = 0.f;
    for (int k = 0; k < KS; ++k) s += part[(size_t)k * tot + idx];
    s += bias[n];
    if (relu) s = fmaxf(s, 0.f);
    out[idx] = s;
}

// ------------------------------------- per-row softmax/argmax + reg + decode
__global__ __launch_bounds__(256) void decode_kernel(
    const float* __restrict__ cls, const float* __restrict__ x2buf,
    const float* __restrict__ reg_w, const float* __restrict__ reg_b,
    const float* __restrict__ props,
    float* __restrict__ scores, int* __restrict__ labels,
    float* __restrict__ boxes, int* __restrict__ valid,
    unsigned int* __restrict__ gmax,
    int n0, int rows, const int* __restrict__ img_h, const int* __restrict__ img_w)
{
    int wid = threadIdx.x >> 6, lane = threadIdx.x & 63;
    int rl = blockIdx.x * 4 + wid;
    if (rl >= rows) return;
    int r = n0 + rl;

    float v0 = (lane < NCLS) ? cls[(size_t)r * NCLS + lane] : -INFINITY;
    float v1 = (lane + 64 < NCLS) ? cls[(size_t)r * NCLS + lane + 64] : -INFINITY;

    float mall = fmaxf(v0, v1);
    for (int s = 32; s; s >>= 1) mall = fmaxf(mall, __shfl_xor(mall, s));

    float bv = -INFINITY; int bi = 1 << 30;
    if (lane >= 1 && lane < NCLS) { bv = v0; bi = lane; }
    if (lane + 64 < NCLS && v1 > bv) { bv = v1; bi = lane + 64; }
    for (int s = 32; s; s >>= 1) {
        float ov = __shfl_xor(bv, s); int oi = __shfl_xor(bi, s);
        if (ov > bv || (ov == bv && oi < bi)) { bv = ov; bi = oi; }
    }

    float den = ((lane < NCLS) ? expf(v0 - mall) : 0.f) +
                ((lane + 64 < NCLS) ? expf(v1 - mall) : 0.f);
    for (int s = 32; s; s >>= 1) den += __shfl_xor(den, s);

    float score = expf(bv - mall) / den;
    int label = bi;

    float dsum[4];
    const float* xr = x2buf + (size_t)rl * HID;
    #pragma unroll
    for (int d = 0; d < 4; ++d) {
        const float* wr2 = reg_w + (size_t)(label * 4 + d) * HID;
        float s = 0.f;
        for (int k = lane; k < HID; k += 64) s = fmaf(xr[k], wr2[k], s);
        for (int sh = 32; sh; sh >>= 1) s += __shfl_xor(s, sh);
        dsum[d] = s + reg_b[label * 4 + d];
    }

    if (lane == 0) {
        float p0 = props[r * 4 + 0], p1 = props[r * 4 + 1];
        float p2 = props[r * 4 + 2], p3 = props[r * 4 + 3];
        float pw = p2 - p0, ph = p3 - p1;
        float pcx = p0 + 0.5f * pw, pcy = p1 + 0.5f * ph;
        float dx = dsum[0], dy = dsum[1];
        float dw = fminf(dsum[2], DW_MAXF), dh = fminf(dsum[3], DW_MAXF);
        float cx = dx * pw + pcx, cy = dy * ph + pcy;
        float bw = expf(dw) * pw, bh = expf(dh) * ph;
        float iw = (float)img_w[0], ih = (float)img_h[0];
        float b0 = fminf(fmaxf(cx - 0.5f * bw, 0.f), iw);
        float b1 = fminf(fmaxf(cy - 0.5f * bh, 0.f), ih);
        float b2 = fminf(fmaxf(cx + 0.5f * bw, 0.f), iw);
        float b3 = fminf(fmaxf(cy + 0.5f * bh, 0.f), ih);
        boxes[r * 4 + 0] = b0; boxes[r * 4 + 1] = b1;
        boxes[r * 4 + 2] = b2; boxes[r * 4 + 3] = b3;
        scores[r] = score; labels[r] = label;
        valid[r] = (score >= 0.05f) && (b2 - b0 >= 1.f) && (b3 - b1 >= 1.f);
        atomicMax(gmax, __float_as_uint(b0)); atomicMax(gmax, __float_as_uint(b1));
        atomicMax(gmax, __float_as_uint(b2)); atomicMax(gmax, __float_as_uint(b3));
    }
}

// ---------------------------------------- stable argsort via O(N^2) ranking
__global__ __launch_bounds__(256) void rank_kernel(
    const float* __restrict__ scores, const int* __restrict__ valid,
    int* __restrict__ order, int N)
{
    int i = blockIdx.x * 256 + threadIdx.x;
    __shared__ float sk[256];
    float ki = INFINITY;
    if (i < N && valid[i]) ki = -scores[i];
    int rank = 0;
    for (int j0 = 0; j0 < N; j0 += 256) {
        int j = j0 + threadIdx.x;
        float kj = INFINITY;
        if (j < N && valid[j]) kj = -scores[j];
        __syncthreads();
        sk[threadIdx.x] = kj;
        __syncthreads();
        int lim = min(256, N - j0);
        for (int jj = 0; jj < lim; ++jj) {
            float k2 = sk[jj];
            int jidx = j0 + jj;
            rank += (k2 < ki) || (k2 == ki && jidx < i);
        }
    }
    if (i < N) order[rank] = i;
}

// --------------------------------- gather sorted arrays + offset boxes + vbits
__global__ __launch_bounds__(256) void sortprep_kernel(
    const int* __restrict__ order, const float* __restrict__ boxes,
    const float* __restrict__ scores, const int* __restrict__ labels,
    const int* __restrict__ valid, const unsigned int* __restrict__ gmax,
    float* __restrict__ sob, float* __restrict__ sarea,
    float* __restrict__ sraw, float* __restrict__ ssc, int* __restrict__ slb,
    unsigned long long* __restrict__ vbits, int N)
{
    int i = blockIdx.x * 256 + threadIdx.x;
    if (i >= N) return;
    int oi = order[i];
    float off = (float)labels[oi] * (__uint_as_float(gmax[0]) + 1.0f);
    float b0 = boxes[oi * 4 + 0] + off, b1 = boxes[oi * 4 + 1] + off;
    float b2 = boxes[oi * 4 + 2] + off, b3 = boxes[oi * 4 + 3] + off;
    sob[i * 4 + 0] = b0; sob[i * 4 + 1] = b1; sob[i * 4 + 2] = b2; sob[i * 4 + 3] = b3;
    sarea[i] = (b2 - b0) * (b3 - b1);
    sraw[i * 4 + 0] = boxes[oi * 4 + 0]; sraw[i * 4 + 1] = boxes[oi * 4 + 1];
    sraw[i * 4 + 2] = boxes[oi * 4 + 2]; sraw[i * 4 + 3] = boxes[oi * 4 + 3];
    ssc[i] = scores[oi]; slb[i] = labels[oi];
    if (valid[oi]) atomicOr(&vbits[i >> 6], 1ull << (i & 63));
}

// ----------------------------------------------- IoU>thresh bitmask (j > i)
__global__ __launch_bounds__(256) void mask_kernel(
    const float* __restrict__ sob, const float* __restrict__ sarea,
    unsigned long long* __restrict__ mask, int N, int NW)
{
    int t = threadIdx.x;
    int w = t & 31, il = t >> 5;
    int i = blockIdx.x * 8 + il;
    if (i >= N || w >= NW) return;
    float4 bi = *(const float4*)(sob + (size_t)i * 4);
    float ai = sarea[i];
    unsigned long long bits = 0;
    int jbase = w * 64;
    for (int b = 0; b < 64; ++b) {
        int j = jbase + b;
        if (j > i && j < N) {
            float4 bj = *(const float4*)(sob + (size_t)j * 4);
            float xl = fmaxf(bi.x, bj.x), yt = fmaxf(bi.y, bj.y);
            float xr = fminf(bi.z, bj.z), yb = fminf(bi.w, bj.w);
            float inter = fmaxf(xr - xl, 0.f) * fmaxf(yb - yt, 0.f);
            float iou = inter / (ai + sarea[j] - inter + 1e-9f);
            if (iou > 0.5f) bits |= 1ull << b;
        }
    }
    mask[(size_t)i * NW + w] = bits;
}

// ------------------------------------------------ serial NMS scan + outputs
__global__ __launch_bounds__(64) void nms_kernel(
    const unsigned long long* __restrict__ mask,
    const unsigned long long* __restrict__ vbits,
    const float* __restrict__ sraw, const float* __restrict__ ssc,
    const int* __restrict__ slb, float* __restrict__ out, int N, int NW)
{
    __shared__ unsigned long long sm[128][32];
    int lane = threadIdx.x;
    unsigned long long supp = 0;
    unsigned long long vw = (lane < NW) ? vbits[lane] : 0ull;
    int cnt = 0;
    for (int base = 0; base < N; base += 128) {
        int rows = min(128, N - base);
        for (int idx = lane; idx < rows * NW; idx += 64)
            sm[idx / NW][idx % NW] = mask[(size_t)(base + idx / NW) * NW + idx % NW];
        __syncthreads();
        for (int ii = 0; ii < rows; ++ii) {
            int i = base + ii;
            int w = i >> 6, b = i & 63;
            unsigned long long sw = __shfl(supp, w);
            unsigned long long vv = __shfl(vw, w);
            bool keep = ((vv >> b) & 1ull) && !((sw >> b) & 1ull);
            if (keep) {
                if (lane < NW) supp |= sm[ii][lane];
                if (cnt < TOPK_OUT) {
                    if (lane < 4) out[cnt * 4 + lane] = sraw[i * 4 + lane];
                    if (lane == 4) out[4 * TOPK_OUT + cnt] = (float)slb[i];
                    if (lane == 5) out[5 * TOPK_OUT + cnt] = ssc[i];
                }
                cnt++;
            }
        }
        __syncthreads();
    }
    for (int s = cnt; s < TOPK_OUT; ++s) {
        if (lane < 4) out[s * 4 + lane] = 0.f;
        if (lane == 4) out[4 * TOPK_OUT + s] = 0.f;
        if (lane == 5) out[5 * TOPK_OUT + s] = 0.f;
    }
}

// --------------------------------------------------------------------------
extern "C" void kernel_launch(void* const* d_in, const int* in_sizes, int n_in,
                              void* d_out, int out_size, void* d_ws, size_t ws_size,
                              hipStream_t stream)
{
    const float* feat  = (const float*)d_in[0];
    const float* props = (const float*)d_in[1];
    const float* fc1_w = (const float*)d_in[2];
    const float* fc1_b = (const float*)d_in[3];
    const float* fc2_w = (const float*)d_in[4];
    const float* fc2_b = (const float*)d_in[5];
    const float* cls_w = (const float*)d_in[6];
    const float* cls_b = (const float*)d_in[7];
    const float* reg_w = (const float*)d_in[8];
    const float* reg_b = (const float*)d_in[9];
    const int* img_h = (const int*)d_in[10];
    const int* img_w = (const int*)d_in[11];
    float* out = (float*)d_out;

    int N = in_sizes[1] / 4;          // 2000
    int NW = (N + 63) >> 6;           // 32

    auto al = [](size_t x) { return (x + 255) & ~(size_t)255; };
    const size_t partBytes = (size_t)256 * GBM * GBN * 4;   // 16.8 MB bound
    size_t fixedBytes =
        al(partBytes) +
        al((size_t)N * NCLS * 4) + al((size_t)N * 4) + al((size_t)N * 4) +
        al((size_t)N * 4) + al((size_t)N * 16) + al((size_t)N * 4) +
        al((size_t)N * 16) + al((size_t)N * 4) + al((size_t)N * 16) +
        al((size_t)N * 4) + al((size_t)N * 4) + al((size_t)NW * 8) + al(4) +
        al((size_t)N * NW * 8);

    int chunk = N;
    while (chunk > 128 &&
           fixedBytes + al((size_t)chunk * DIM * 4) + 2 * al((size_t)chunk * HID * 4) > ws_size)
        chunk = (chunk + 1) / 2;

    char* p = (char*)d_ws;
    auto grab = [&](size_t bytes) { char* q = p; p += al(bytes); return q; };
    float* pooled = (float*)grab((size_t)chunk * DIM * 4);
    float* x1buf  = (float*)grab((size_t)chunk * HID * 4);
    float* x2buf  = (float*)grab((size_t)chunk * HID * 4);
    float* part   = (float*)grab(partBytes);
    float* cls    = (float*)grab((size_t)N * NCLS * 4);
    float* scores = (float*)grab((size_t)N * 4);
    int*   labels = (int*)grab((size_t)N * 4);
    int*   valid  = (int*)grab((size_t)N * 4);
    float* boxes  = (float*)grab((size_t)N * 16);
    int*   order  = (int*)grab((size_t)N * 4);
    float* sob    = (float*)grab((size_t)N * 16);
    float* sarea  = (float*)grab((size_t)N * 4);
    float* sraw   = (float*)grab((size_t)N * 16);
    float* ssc    = (float*)grab((size_t)N * 4);
    int*   slb    = (int*)grab((size_t)N * 4);
    unsigned long long* vbits = (unsigned long long*)grab((size_t)NW * 8);
    unsigned int* gmax = (unsigned int*)grab(4);
    unsigned long long* maskp = (unsigned long long*)grab((size_t)N * NW * 8);

    hipMemsetAsync(vbits, 0, (size_t)NW * 8, stream);
    hipMemsetAsync(gmax, 0, 4, stream);

    auto gemm3 = [&](const float* Ain, const float* Win, const float* bias,
                     float* Cout, int M_, int N_, int K_, int relu) {
        int gm = (M_ + GBM - 1) / GBM;
        int gn = (N_ + GBN - 1) / GBN;
        int ksteps = K_ / GBK;
        int KS = 256 / (gm * gn);
        if (KS < 1) KS = 1;
        if (KS > 32) KS = 32;
        if (KS > ksteps) KS = ksteps;
        dim3 g(gn, gm, KS);
        gemm3_kernel<<<g, 256, 0, stream>>>(Ain, Win, part, M_, N_, K_, ksteps, KS);
        int tot = M_ * N_;
        reduce_kernel<<<(tot + 255) / 256, 256, 0, stream>>>(part, bias, Cout,
                                                             M_, N_, KS, relu);
    };

    for (int n0 = 0; n0 < N; n0 += chunk) {
        int rows = min(chunk, N - n0);
        {
            int total = rows * DIM;
            roi_pool_kernel<<<(total + 255) / 256, 256, 0, stream>>>(
                feat, props, pooled, n0, rows, img_h, img_w);
        }
        gemm3(pooled, fc1_w, fc1_b, x1buf, rows, HID, DIM, 1);
        gemm3(x1buf, fc2_w, fc2_b, x2buf, rows, HID, HID, 1);
        gemm3(x2buf, cls_w, cls_b, cls + (size_t)n0 * NCLS, rows, NCLS, HID, 0);
        decode_kernel<<<(rows + 3) / 4, 256, 0, stream>>>(
            cls, x2buf, reg_w, reg_b, props, scores, labels, boxes, valid,
            gmax, n0, rows, img_h, img_w);
    }

    rank_kernel<<<(N + 255) / 256, 256, 0, stream>>>(scores, valid, order, N);
    sortprep_kernel<<<(N + 255) / 256, 256, 0, stream>>>(
        order, boxes, scores, labels, valid, gmax, sob, sarea, sraw, ssc, slb,
        vbits, N);
    mask_kernel<<<(N + 7) / 8, 256, 0, stream>>>(sob, sarea, maskp, N, NW);
    nms_kernel<<<1, 64, 0, stream>>>(maskp, vbits, sraw, ssc, slb, out, N, NW);
}

// Round 3
// 1105.061 us; speedup vs baseline: 1.8207x; 1.7160x over previous
//
#include <hip/hip_runtime.h>
#include <cstdint>

#define POOLK 7
#define NCLS 91
#define FH 50
#define FW 50
#define FCH 256
#define DIM (FCH * POOLK * POOLK) /* 12544 */
#define HID 1024
#define TOPK_OUT 100
#define DW_MAXF 4.135166556742356f

typedef __attribute__((ext_vector_type(8))) short short8;
typedef __attribute__((ext_vector_type(4))) float f32x4;

__device__ __forceinline__ unsigned short f2bf(float x)
{
    unsigned u = __float_as_uint(x);
    return (unsigned short)((u + 0x7FFFu + ((u >> 16) & 1u)) >> 16);
}

// ---------------------------------------------------------------- ROI pool -> bf16
__global__ __launch_bounds__(256) void roi_pool_kernel(
    const float* __restrict__ feat, const float* __restrict__ props,
    unsigned short* __restrict__ pooled, int n0, int rows,
    const int* __restrict__ img_h, const int* __restrict__ img_w)
{
    int tid = blockIdx.x * 256 + threadIdx.x;
    int total = rows * DIM;
    if (tid >= total) return;
    int cell = tid % 49;
    int c    = (tid / 49) % FCH;
    int rl   = tid / DIM;
    int py = cell / 7, px = cell % 7;
    int n = n0 + rl;

    float scale = (float)fmin((double)FH / (double)img_h[0],
                              (double)FW / (double)img_w[0]);
    float x1 = rintf(props[n * 4 + 0] * scale);
    float y1 = rintf(props[n * 4 + 1] * scale);
    float x2 = rintf(props[n * 4 + 2] * scale);
    float y2 = rintf(props[n * 4 + 3] * scale);
    float roiw = fmaxf(x2 - x1 + 1.f, 1.f);
    float roih = fmaxf(y2 - y1 + 1.f, 1.f);

    float hsf = fminf(fmaxf(floorf((float)py * roih / 7.f) + y1, 0.f), (float)FH);
    float hef = fminf(fmaxf(ceilf(((float)py + 1.f) * roih / 7.f) + y1, 0.f), (float)FH);
    float wsf = fminf(fmaxf(floorf((float)px * roiw / 7.f) + x1, 0.f), (float)FW);
    float wef = fminf(fmaxf(ceilf(((float)px + 1.f) * roiw / 7.f) + x1, 0.f), (float)FW);
    int h0 = (int)hsf, h1 = (int)hef, w0 = (int)wsf, w1 = (int)wef;

    float m = 0.f;
    if (h0 < h1 && w0 < w1) {
        m = -INFINITY;
        const float* fp = feat + (size_t)c * (FH * FW);
        for (int h = h0; h < h1; ++h) {
            const float* rowp = fp + h * FW;
            for (int w = w0; w < w1; ++w) m = fmaxf(m, rowp[w]);
        }
    }
    pooled[(size_t)rl * DIM + c * 49 + cell] = f2bf(m);
}

// --------------------------------------------------------- fp32 -> bf16 weights
__global__ __launch_bounds__(256) void wconv_kernel(
    const float* __restrict__ w, unsigned short* __restrict__ wh, int n4)
{
    int i = blockIdx.x * 256 + threadIdx.x;
    if (i >= n4) return;
    float4 v = ((const float4*)w)[i];
    ushort4 o;
    o.x = f2bf(v.x); o.y = f2bf(v.y); o.z = f2bf(v.z); o.w = f2bf(v.w);
    ((ushort4*)wh)[i] = o;
}

// ------------------------------------------------- split-K MFMA bf16 GEMM
// A: M x K bf16 row-major, B(=W): N x K bf16 row-major, C partials fp32
#define GBM 128
#define GBN 128
#define GBK 64

typedef __attribute__((address_space(1))) void* gas_p;
typedef __attribute__((address_space(3))) void* las_p;
__device__ __forceinline__ void async16(void* l, const void* g)
{
    __builtin_amdgcn_global_load_lds((gas_p)g, (las_p)l, 16, 0, 0);
}

__global__ __launch_bounds__(256, 2) void gemm_bf16_kernel(
    const unsigned short* __restrict__ A, const unsigned short* __restrict__ B,
    float* __restrict__ part, int M, int N, int K, int ksteps, int KS)
{
    __shared__ unsigned short ldsA[2][GBM * GBK];
    __shared__ unsigned short ldsB[2][GBN * GBK];

    int t = threadIdx.x;
    int lane = t & 63, wave = t >> 6;
    int m0 = blockIdx.y * GBM, n0 = blockIdx.x * GBN;

    int steps_per = (ksteps + KS - 1) / KS;
    int ks0 = blockIdx.z * steps_per;
    int ks1 = min(ksteps, ks0 + steps_per);
    int nt = ks1 - ks0;

    // staging geometry: instr i covers 8 rows x 128B; lane -> row lrow, slot lslot
    // LDS is written LINEARLY by global_load_lds; we pre-swizzle the GLOBAL
    // source so that LDS slot p of row r holds global k-slot (p ^ (r&7)).
    int lrow  = lane >> 3;            // 0..7  (== tile_row & 7 by construction)
    int lslot = (lane & 7) ^ lrow;    // pre-swizzled source slot
    const unsigned short* aSrc[4];
    const unsigned short* bSrc[4];
    #pragma unroll
    for (int i = 0; i < 4; ++i) {
        int r = wave * 32 + i * 8 + lrow;
        int gm = min(m0 + r, M - 1);
        int gn = min(n0 + r, N - 1);
        aSrc[i] = A + (size_t)gm * K + lslot * 8;
        bSrc[i] = B + (size_t)gn * K + lslot * 8;
    }

    int wr = wave >> 1, wc = wave & 1;   // 2x2 waves, each owns 64x64
    int fr = lane & 15, fq = lane >> 4;

    f32x4 acc[4][4] = {};

    auto STAGE = [&](int buf, int kt) {
        int koff = kt * GBK;
        #pragma unroll
        for (int i = 0; i < 4; ++i) {
            async16(&ldsA[buf][(wave * 32 + i * 8) * GBK], aSrc[i] + koff);
            async16(&ldsB[buf][(wave * 32 + i * 8) * GBK], bSrc[i] + koff);
        }
    };

    auto COMPUTE = [&](int buf) {
        #pragma unroll
        for (int h = 0; h < 2; ++h) {
            short8 af[4], bfr[4];
            #pragma unroll
            for (int mi = 0; mi < 4; ++mi) {
                int r = wr * 64 + mi * 16 + fr;
                int idx = r * GBK + (((h * 4 + fq) ^ (r & 7)) << 3);
                af[mi] = *(const short8*)&ldsA[buf][idx];
            }
            #pragma unroll
            for (int ni = 0; ni < 4; ++ni) {
                int r = wc * 64 + ni * 16 + fr;
                int idx = r * GBK + (((h * 4 + fq) ^ (r & 7)) << 3);
                bfr[ni] = *(const short8*)&ldsB[buf][idx];
            }
            #pragma unroll
            for (int mi = 0; mi < 4; ++mi)
                #pragma unroll
                for (int ni = 0; ni < 4; ++ni)
                    acc[mi][ni] = __builtin_amdgcn_mfma_f32_16x16x32_bf16(
                        af[mi], bfr[ni], acc[mi][ni], 0, 0, 0);
        }
    };

    if (nt > 0) STAGE(0, ks0);
    __syncthreads();
    int cur = 0;
    for (int ts = 0; ts < nt; ++ts) {
        if (ts + 1 < nt) STAGE(cur ^ 1, ks0 + ts + 1);
        COMPUTE(cur);
        __syncthreads();
        cur ^= 1;
    }

    // C: col = lane&15, row = (lane>>4)*4 + reg  (m89-verified)
    float* pbase = part + (size_t)blockIdx.z * M * N;
    #pragma unroll
    for (int mi = 0; mi < 4; ++mi) {
        #pragma unroll
        for (int ni = 0; ni < 4; ++ni) {
            int col = n0 + wc * 64 + ni * 16 + fr;
            if (col >= N) continue;
            #pragma unroll
            for (int j = 0; j < 4; ++j) {
                int row = m0 + wr * 64 + mi * 16 + fq * 4 + j;
                if (row < M) pbase[(size_t)row * N + col] = acc[mi][ni][j];
            }
        }
    }
}

// ------------------------------- split-K reduce + bias (+relu) -> f32/bf16
__global__ __launch_bounds__(256) void reduce_kernel(
    const float* __restrict__ part, const float* __restrict__ bias,
    float* __restrict__ outf, unsigned short* __restrict__ outh,
    int M, int N, int KS, int relu)
{
    int idx = blockIdx.x * 256 + threadIdx.x;
    int tot = M * N;
    if (idx >= tot) return;
    int n = idx % N;
    float s = 0.f;
    for (int k = 0; k < KS; ++k) s += part[(size_t)k * tot + idx];
    s += bias[n];
    if (relu) s = fmaxf(s, 0.f);
    if (outf) outf[idx] = s;
    if (outh) outh[idx] = f2bf(s);
}

// ------------------------------------- per-row softmax/argmax + reg + decode
__global__ __launch_bounds__(256) void decode_kernel(
    const float* __restrict__ cls, const float* __restrict__ x2buf,
    const float* __restrict__ reg_w, const float* __restrict__ reg_b,
    const float* __restrict__ props,
    float* __restrict__ scores, int* __restrict__ labels,
    float* __restrict__ boxes, int* __restrict__ valid,
    unsigned int* __restrict__ gmax,
    int n0, int rows, const int* __restrict__ img_h, const int* __restrict__ img_w)
{
    int wid = threadIdx.x >> 6, lane = threadIdx.x & 63;
    int rl = blockIdx.x * 4 + wid;
    if (rl >= rows) return;
    int r = n0 + rl;

    float v0 = (lane < NCLS) ? cls[(size_t)r * NCLS + lane] : -INFINITY;
    float v1 = (lane + 64 < NCLS) ? cls[(size_t)r * NCLS + lane + 64] : -INFINITY;

    float mall = fmaxf(v0, v1);
    for (int s = 32; s; s >>= 1) mall = fmaxf(mall, __shfl_xor(mall, s));

    float bv = -INFINITY; int bi = 1 << 30;
    if (lane >= 1 && lane < NCLS) { bv = v0; bi = lane; }
    if (lane + 64 < NCLS && v1 > bv) { bv = v1; bi = lane + 64; }
    for (int s = 32; s; s >>= 1) {
        float ov = __shfl_xor(bv, s); int oi = __shfl_xor(bi, s);
        if (ov > bv || (ov == bv && oi < bi)) { bv = ov; bi = oi; }
    }

    float den = ((lane < NCLS) ? expf(v0 - mall) : 0.f) +
                ((lane + 64 < NCLS) ? expf(v1 - mall) : 0.f);
    for (int s = 32; s; s >>= 1) den += __shfl_xor(den, s);

    float score = expf(bv - mall) / den;
    int label = bi;

    float dsum[4];
    const float* xr = x2buf + (size_t)rl * HID;
    #pragma unroll
    for (int d = 0; d < 4; ++d) {
        const float* wr2 = reg_w + (size_t)(label * 4 + d) * HID;
        float s = 0.f;
        for (int k = lane; k < HID; k += 64) s = fmaf(xr[k], wr2[k], s);
        for (int sh = 32; sh; sh >>= 1) s += __shfl_xor(s, sh);
        dsum[d] = s + reg_b[label * 4 + d];
    }

    if (lane == 0) {
        float p0 = props[r * 4 + 0], p1 = props[r * 4 + 1];
        float p2 = props[r * 4 + 2], p3 = props[r * 4 + 3];
        float pw = p2 - p0, ph = p3 - p1;
        float pcx = p0 + 0.5f * pw, pcy = p1 + 0.5f * ph;
        float dx = dsum[0], dy = dsum[1];
        float dw = fminf(dsum[2], DW_MAXF), dh = fminf(dsum[3], DW_MAXF);
        float cx = dx * pw + pcx, cy = dy * ph + pcy;
        float bw = expf(dw) * pw, bh = expf(dh) * ph;
        float iw = (float)img_w[0], ih = (float)img_h[0];
        float b0 = fminf(fmaxf(cx - 0.5f * bw, 0.f), iw);
        float b1 = fminf(fmaxf(cy - 0.5f * bh, 0.f), ih);
        float b2 = fminf(fmaxf(cx + 0.5f * bw, 0.f), iw);
        float b3 = fminf(fmaxf(cy + 0.5f * bh, 0.f), ih);
        boxes[r * 4 + 0] = b0; boxes[r * 4 + 1] = b1;
        boxes[r * 4 + 2] = b2; boxes[r * 4 + 3] = b3;
        scores[r] = score; labels[r] = label;
        valid[r] = (score >= 0.05f) && (b2 - b0 >= 1.f) && (b3 - b1 >= 1.f);
        atomicMax(gmax, __float_as_uint(b0)); atomicMax(gmax, __float_as_uint(b1));
        atomicMax(gmax, __float_as_uint(b2)); atomicMax(gmax, __float_as_uint(b3));
    }
}

// ---------------------------------------- stable argsort via O(N^2) ranking
__global__ __launch_bounds__(256) void rank_kernel(
    const float* __restrict__ scores, const int* __restrict__ valid,
    int* __restrict__ order, int N)
{
    int i = blockIdx.x * 256 + threadIdx.x;
    __shared__ float sk[256];
    float ki = INFINITY;
    if (i < N && valid[i]) ki = -scores[i];
    int rank = 0;
    for (int j0 = 0; j0 < N; j0 += 256) {
        int j = j0 + threadIdx.x;
        float kj = INFINITY;
        if (j < N && valid[j]) kj = -scores[j];
        __syncthreads();
        sk[threadIdx.x] = kj;
        __syncthreads();
        int lim = min(256, N - j0);
        for (int jj = 0; jj < lim; ++jj) {
            float k2 = sk[jj];
            int jidx = j0 + jj;
            rank += (k2 < ki) || (k2 == ki && jidx < i);
        }
    }
    if (i < N) order[rank] = i;
}

// --------------------------------- gather sorted arrays + offset boxes + vbits
__global__ __launch_bounds__(256) void sortprep_kernel(
    const int* __restrict__ order, const float* __restrict__ boxes,
    const float* __restrict__ scores, const int* __restrict__ labels,
    const int* __restrict__ valid, const unsigned int* __restrict__ gmax,
    float* __restrict__ sob, float* __restrict__ sarea,
    float* __restrict__ sraw, float* __restrict__ ssc, int* __restrict__ slb,
    unsigned long long* __restrict__ vbits, int N)
{
    int i = blockIdx.x * 256 + threadIdx.x;
    if (i >= N) return;
    int oi = order[i];
    float off = (float)labels[oi] * (__uint_as_float(gmax[0]) + 1.0f);
    float b0 = boxes[oi * 4 + 0] + off, b1 = boxes[oi * 4 + 1] + off;
    float b2 = boxes[oi * 4 + 2] + off, b3 = boxes[oi * 4 + 3] + off;
    sob[i * 4 + 0] = b0; sob[i * 4 + 1] = b1; sob[i * 4 + 2] = b2; sob[i * 4 + 3] = b3;
    sarea[i] = (b2 - b0) * (b3 - b1);
    sraw[i * 4 + 0] = boxes[oi * 4 + 0]; sraw[i * 4 + 1] = boxes[oi * 4 + 1];
    sraw[i * 4 + 2] = boxes[oi * 4 + 2]; sraw[i * 4 + 3] = boxes[oi * 4 + 3];
    ssc[i] = scores[oi]; slb[i] = labels[oi];
    if (valid[oi]) atomicOr(&vbits[i >> 6], 1ull << (i & 63));
}

// ----------------------------------------------- IoU>thresh bitmask (j > i)
__global__ __launch_bounds__(256) void mask_kernel(
    const float* __restrict__ sob, const float* __restrict__ sarea,
    unsigned long long* __restrict__ mask, int N, int NW)
{
    int t = threadIdx.x;
    int w = t & 31, il = t >> 5;
    int i = blockIdx.x * 8 + il;
    if (i >= N || w >= NW) return;
    float4 bi = *(const float4*)(sob + (size_t)i * 4);
    float ai = sarea[i];
    unsigned long long bits = 0;
    int jbase = w * 64;
    for (int b = 0; b < 64; ++b) {
        int j = jbase + b;
        if (j > i && j < N) {
            float4 bj = *(const float4*)(sob + (size_t)j * 4);
            float xl = fmaxf(bi.x, bj.x), yt = fmaxf(bi.y, bj.y);
            float xr = fminf(bi.z, bj.z), yb = fminf(bi.w, bj.w);
            float inter = fmaxf(xr - xl, 0.f) * fmaxf(yb - yt, 0.f);
            float iou = inter / (ai + sarea[j] - inter + 1e-9f);
            if (iou > 0.5f) bits |= 1ull << b;
        }
    }
    mask[(size_t)i * NW + w] = bits;
}

// ------------------------------------------------ serial NMS scan + outputs
__global__ __launch_bounds__(64) void nms_kernel(
    const unsigned long long* __restrict__ mask,
    const unsigned long long* __restrict__ vbits,
    const float* __restrict__ sraw, const float* __restrict__ ssc,
    const int* __restrict__ slb, float* __restrict__ out, int N, int NW)
{
    __shared__ unsigned long long sm[128][32];
    int lane = threadIdx.x;
    unsigned long long supp = 0;
    unsigned long long vw = (lane < NW) ? vbits[lane] : 0ull;
    int cnt = 0;
    for (int base = 0; base < N; base += 128) {
        int rows = min(128, N - base);
        for (int idx = lane; idx < rows * NW; idx += 64)
            sm[idx / NW][idx % NW] = mask[(size_t)(base + idx / NW) * NW + idx % NW];
        __syncthreads();
        for (int ii = 0; ii < rows; ++ii) {
            int i = base + ii;
            int w = i >> 6, b = i & 63;
            unsigned long long sw = __shfl(supp, w);
            unsigned long long vv = __shfl(vw, w);
            bool keep = ((vv >> b) & 1ull) && !((sw >> b) & 1ull);
            if (keep) {
                if (lane < NW) supp |= sm[ii][lane];
                if (cnt < TOPK_OUT) {
                    if (lane < 4) out[cnt * 4 + lane] = sraw[i * 4 + lane];
                    if (lane == 4) out[4 * TOPK_OUT + cnt] = (float)slb[i];
                    if (lane == 5) out[5 * TOPK_OUT + cnt] = ssc[i];
                }
                cnt++;
            }
        }
        __syncthreads();
    }
    for (int s = cnt; s < TOPK_OUT; ++s) {
        if (lane < 4) out[s * 4 + lane] = 0.f;
        if (lane == 4) out[4 * TOPK_OUT + s] = 0.f;
        if (lane == 5) out[5 * TOPK_OUT + s] = 0.f;
    }
}

// --------------------------------------------------------------------------
extern "C" void kernel_launch(void* const* d_in, const int* in_sizes, int n_in,
                              void* d_out, int out_size, void* d_ws, size_t ws_size,
                              hipStream_t stream)
{
    const float* feat  = (const float*)d_in[0];
    const float* props = (const float*)d_in[1];
    const float* fc1_w = (const float*)d_in[2];
    const float* fc1_b = (const float*)d_in[3];
    const float* fc2_w = (const float*)d_in[4];
    const float* fc2_b = (const float*)d_in[5];
    const float* cls_w = (const float*)d_in[6];
    const float* cls_b = (const float*)d_in[7];
    const float* reg_w = (const float*)d_in[8];
    const float* reg_b = (const float*)d_in[9];
    const int* img_h = (const int*)d_in[10];
    const int* img_w = (const int*)d_in[11];
    float* out = (float*)d_out;

    int N = in_sizes[1] / 4;          // 2000
    int NW = (N + 63) >> 6;           // 32
    int n_fc1w = in_sizes[2];         // 12845056
    int n_fc2w = in_sizes[4];         // 1048576
    int n_clsw = in_sizes[6];         // 93184

    auto al = [](size_t x) { return (x + 255) & ~(size_t)255; };

    size_t miscBytes =
        al((size_t)N * NCLS * 4) +                    // cls
        al((size_t)N * 4) * 6 +                       // scores/labels/valid/order/sarea/ssc
        al((size_t)N * 16) * 3 +                      // boxes/sob/sraw
        al((size_t)N * 4) +                           // slb
        al((size_t)NW * 8) + al(4) +                  // vbits, gmax
        al((size_t)N * NW * 8);                       // mask
    size_t wBytes = al((size_t)n_fc1w * 2) + al((size_t)n_fc2w * 2) +
                    al((size_t)n_clsw * 2);

    size_t partCap = 32u << 20;       // 32 MB
    int chunk = N;
    auto need = [&](int ch, size_t pc) {
        return al(pc) + wBytes + miscBytes +
               al((size_t)ch * DIM * 2) +             // pooled bf16
               al((size_t)ch * HID * 2) +             // x1 bf16
               al((size_t)ch * HID * 4) +             // x2 f32
               al((size_t)ch * HID * 2);              // x2 bf16
    };
    while (need(chunk, partCap) > ws_size && chunk > 125) chunk = (chunk + 1) / 2;
    while (need(chunk, partCap) > ws_size && partCap > ((size_t)chunk * HID * 4 + (4u<<20)))
        partCap >>= 1;

    char* p = (char*)d_ws;
    auto grab = [&](size_t bytes) { char* q = p; p += al(bytes); return q; };
    float* part = (float*)grab(partCap);
    unsigned short* fc1wh = (unsigned short*)grab((size_t)n_fc1w * 2);
    unsigned short* fc2wh = (unsigned short*)grab((size_t)n_fc2w * 2);
    unsigned short* clswh = (unsigned short*)grab((size_t)n_clsw * 2);
    unsigned short* pooledh = (unsigned short*)grab((size_t)chunk * DIM * 2);
    unsigned short* x1h = (unsigned short*)grab((size_t)chunk * HID * 2);
    float* x2f = (float*)grab((size_t)chunk * HID * 4);
    unsigned short* x2h = (unsigned short*)grab((size_t)chunk * HID * 2);
    float* cls    = (float*)grab((size_t)N * NCLS * 4);
    float* scores = (float*)grab((size_t)N * 4);
    int*   labels = (int*)grab((size_t)N * 4);
    int*   valid  = (int*)grab((size_t)N * 4);
    float* boxes  = (float*)grab((size_t)N * 16);
    int*   order  = (int*)grab((size_t)N * 4);
    float* sob    = (float*)grab((size_t)N * 16);
    float* sarea  = (float*)grab((size_t)N * 4);
    float* sraw   = (float*)grab((size_t)N * 16);
    float* ssc    = (float*)grab((size_t)N * 4);
    int*   slb    = (int*)grab((size_t)N * 4);
    unsigned long long* vbits = (unsigned long long*)grab((size_t)NW * 8);
    unsigned int* gmax = (unsigned int*)grab(4);
    unsigned long long* maskp = (unsigned long long*)grab((size_t)N * NW * 8);

    hipMemsetAsync(vbits, 0, (size_t)NW * 8, stream);
    hipMemsetAsync(gmax, 0, 4, stream);

    // weight conversions (once per launch)
    wconv_kernel<<<(n_fc1w / 4 + 255) / 256, 256, 0, stream>>>(fc1_w, fc1wh, n_fc1w / 4);
    wconv_kernel<<<(n_fc2w / 4 + 255) / 256, 256, 0, stream>>>(fc2_w, fc2wh, n_fc2w / 4);
    wconv_kernel<<<(n_clsw / 4 + 255) / 256, 256, 0, stream>>>(cls_w, clswh, n_clsw / 4);

    auto gemmb = [&](const unsigned short* Ah, const unsigned short* Bh,
                     const float* bias, float* outf, unsigned short* outh,
                     int M_, int N_, int K_, int relu) {
        int gm = (M_ + GBM - 1) / GBM;
        int gn = (N_ + GBN - 1) / GBN;
        int ksteps = K_ / GBK;
        int KS = 512 / (gm * gn);
        if (KS < 1) KS = 1;
        if (KS > 16) KS = 16;
        long ksMem = (long)(partCap / ((size_t)M_ * N_ * 4));
        if (KS > ksMem) KS = (int)ksMem;
        if (KS > ksteps) KS = ksteps;
        if (KS < 1) KS = 1;
        dim3 g(gn, gm, KS);
        gemm_bf16_kernel<<<g, 256, 0, stream>>>(Ah, Bh, part, M_, N_, K_, ksteps, KS);
        int tot = M_ * N_;
        reduce_kernel<<<(tot + 255) / 256, 256, 0, stream>>>(part, bias, outf, outh,
                                                             M_, N_, KS, relu);
    };

    for (int n0 = 0; n0 < N; n0 += chunk) {
        int rows = min(chunk, N - n0);
        {
            int total = rows * DIM;
            roi_pool_kernel<<<(total + 255) / 256, 256, 0, stream>>>(
                feat, props, pooledh, n0, rows, img_h, img_w);
        }
        gemmb(pooledh, fc1wh, fc1_b, nullptr, x1h, rows, HID, DIM, 1);
        gemmb(x1h, fc2wh, fc2_b, x2f, x2h, rows, HID, HID, 1);
        gemmb(x2h, clswh, cls_b, cls + (size_t)n0 * NCLS, nullptr, rows, NCLS, HID, 0);
        decode_kernel<<<(rows + 3) / 4, 256, 0, stream>>>(
            cls, x2f, reg_w, reg_b, props, scores, labels, boxes, valid,
            gmax, n0, rows, img_h, img_w);
    }

    rank_kernel<<<(N + 255) / 256, 256, 0, stream>>>(scores, valid, order, N);
    sortprep_kernel<<<(N + 255) / 256, 256, 0, stream>>>(
        order, boxes, scores, labels, valid, gmax, sob, sarea, sraw, ssc, slb,
        vbits, N);
    mask_kernel<<<(N + 7) / 8, 256, 0, stream>>>(sob, sarea, maskp, N, NW);
    nms_kernel<<<1, 64, 0, stream>>>(maskp, vbits, sraw, ssc, slb, out, N, NW);
}

// Round 4
// 586.128 us; speedup vs baseline: 3.4327x; 1.8854x over previous
//
#include <hip/hip_runtime.h>
#include <cstdint>

#define POOLK 7
#define NCLS 91
#define FH 50
#define FW 50
#define FCH 256
#define DIM (FCH * POOLK * POOLK) /* 12544 */
#define HID 1024
#define TOPK_OUT 100
#define DW_MAXF 4.135166556742356f

typedef __attribute__((ext_vector_type(8))) short short8;
typedef __attribute__((ext_vector_type(4))) float f32x4;

__device__ __forceinline__ unsigned short f2bf(float x)
{
    unsigned u = __float_as_uint(x);
    return (unsigned short)((u + 0x7FFFu + ((u >> 16) & 1u)) >> 16);
}

// ---------------------------------------------------------------- ROI pool -> bf16
__global__ __launch_bounds__(256) void roi_pool_kernel(
    const float* __restrict__ feat, const float* __restrict__ props,
    unsigned short* __restrict__ pooled, int n0, int rows,
    const int* __restrict__ img_h, const int* __restrict__ img_w)
{
    int tid = blockIdx.x * 256 + threadIdx.x;
    int total = rows * DIM;
    if (tid >= total) return;
    int cell = tid % 49;
    int c    = (tid / 49) % FCH;
    int rl   = tid / DIM;
    int py = cell / 7, px = cell % 7;
    int n = n0 + rl;

    float scale = (float)fmin((double)FH / (double)img_h[0],
                              (double)FW / (double)img_w[0]);
    float x1 = rintf(props[n * 4 + 0] * scale);
    float y1 = rintf(props[n * 4 + 1] * scale);
    float x2 = rintf(props[n * 4 + 2] * scale);
    float y2 = rintf(props[n * 4 + 3] * scale);
    float roiw = fmaxf(x2 - x1 + 1.f, 1.f);
    float roih = fmaxf(y2 - y1 + 1.f, 1.f);

    float hsf = fminf(fmaxf(floorf((float)py * roih / 7.f) + y1, 0.f), (float)FH);
    float hef = fminf(fmaxf(ceilf(((float)py + 1.f) * roih / 7.f) + y1, 0.f), (float)FH);
    float wsf = fminf(fmaxf(floorf((float)px * roiw / 7.f) + x1, 0.f), (float)FW);
    float wef = fminf(fmaxf(ceilf(((float)px + 1.f) * roiw / 7.f) + x1, 0.f), (float)FW);
    int h0 = (int)hsf, h1 = (int)hef, w0 = (int)wsf, w1 = (int)wef;

    float m = 0.f;
    if (h0 < h1 && w0 < w1) {
        m = -INFINITY;
        const float* fp = feat + (size_t)c * (FH * FW);
        for (int h = h0; h < h1; ++h) {
            const float* rowp = fp + h * FW;
            for (int w = w0; w < w1; ++w) m = fmaxf(m, rowp[w]);
        }
    }
    pooled[(size_t)rl * DIM + c * 49 + cell] = f2bf(m);
}

// --------------------------------------------------------- fp32 -> bf16 weights
__global__ __launch_bounds__(256) void wconv_kernel(
    const float* __restrict__ w, unsigned short* __restrict__ wh, int n4)
{
    int i = blockIdx.x * 256 + threadIdx.x;
    if (i >= n4) return;
    float4 v = ((const float4*)w)[i];
    ushort4 o;
    o.x = f2bf(v.x); o.y = f2bf(v.y); o.z = f2bf(v.z); o.w = f2bf(v.w);
    ((ushort4*)wh)[i] = o;
}

// ------------------------------------------------- split-K MFMA bf16 GEMM
// A: M x K bf16 row-major, B(=W): N x K bf16 row-major, C partials fp32
#define GBM 128
#define GBN 128
#define GBK 64

typedef __attribute__((address_space(1))) void* gas_p;
typedef __attribute__((address_space(3))) void* las_p;
__device__ __forceinline__ void async16(void* l, const void* g)
{
    __builtin_amdgcn_global_load_lds((gas_p)g, (las_p)l, 16, 0, 0);
}

__global__ __launch_bounds__(256, 2) void gemm_bf16_kernel(
    const unsigned short* __restrict__ A, const unsigned short* __restrict__ B,
    float* __restrict__ part, int M, int N, int K, int ksteps, int KS)
{
    __shared__ unsigned short ldsA[2][GBM * GBK];
    __shared__ unsigned short ldsB[2][GBN * GBK];

    int t = threadIdx.x;
    int lane = t & 63, wave = t >> 6;
    int m0 = blockIdx.y * GBM, n0 = blockIdx.x * GBN;

    int steps_per = (ksteps + KS - 1) / KS;
    int ks0 = blockIdx.z * steps_per;
    int ks1 = min(ksteps, ks0 + steps_per);
    int nt = ks1 - ks0;

    // staging geometry: instr i covers 8 rows x 128B; lane -> row lrow, slot lslot
    // LDS is written LINEARLY by global_load_lds; we pre-swizzle the GLOBAL
    // source so that LDS slot p of row r holds global k-slot (p ^ (r&7)).
    int lrow  = lane >> 3;            // 0..7  (== tile_row & 7 by construction)
    int lslot = (lane & 7) ^ lrow;    // pre-swizzled source slot
    const unsigned short* aSrc[4];
    const unsigned short* bSrc[4];
    #pragma unroll
    for (int i = 0; i < 4; ++i) {
        int r = wave * 32 + i * 8 + lrow;
        int gm = min(m0 + r, M - 1);
        int gn = min(n0 + r, N - 1);
        aSrc[i] = A + (size_t)gm * K + lslot * 8;
        bSrc[i] = B + (size_t)gn * K + lslot * 8;
    }

    int wr = wave >> 1, wc = wave & 1;   // 2x2 waves, each owns 64x64
    int fr = lane & 15, fq = lane >> 4;

    f32x4 acc[4][4] = {};

    auto STAGE = [&](int buf, int kt) {
        int koff = kt * GBK;
        #pragma unroll
        for (int i = 0; i < 4; ++i) {
            async16(&ldsA[buf][(wave * 32 + i * 8) * GBK], aSrc[i] + koff);
            async16(&ldsB[buf][(wave * 32 + i * 8) * GBK], bSrc[i] + koff);
        }
    };

    auto COMPUTE = [&](int buf) {
        #pragma unroll
        for (int h = 0; h < 2; ++h) {
            short8 af[4], bfr[4];
            #pragma unroll
            for (int mi = 0; mi < 4; ++mi) {
                int r = wr * 64 + mi * 16 + fr;
                int idx = r * GBK + (((h * 4 + fq) ^ (r & 7)) << 3);
                af[mi] = *(const short8*)&ldsA[buf][idx];
            }
            #pragma unroll
            for (int ni = 0; ni < 4; ++ni) {
                int r = wc * 64 + ni * 16 + fr;
                int idx = r * GBK + (((h * 4 + fq) ^ (r & 7)) << 3);
                bfr[ni] = *(const short8*)&ldsB[buf][idx];
            }
            #pragma unroll
            for (int mi = 0; mi < 4; ++mi)
                #pragma unroll
                for (int ni = 0; ni < 4; ++ni)
                    acc[mi][ni] = __builtin_amdgcn_mfma_f32_16x16x32_bf16(
                        af[mi], bfr[ni], acc[mi][ni], 0, 0, 0);
        }
    };

    if (nt > 0) STAGE(0, ks0);
    __syncthreads();
    int cur = 0;
    for (int ts = 0; ts < nt; ++ts) {
        if (ts + 1 < nt) STAGE(cur ^ 1, ks0 + ts + 1);
        COMPUTE(cur);
        __syncthreads();
        cur ^= 1;
    }

    // C: col = lane&15, row = (lane>>4)*4 + reg  (m89-verified)
    float* pbase = part + (size_t)blockIdx.z * M * N;
    #pragma unroll
    for (int mi = 0; mi < 4; ++mi) {
        #pragma unroll
        for (int ni = 0; ni < 4; ++ni) {
            int col = n0 + wc * 64 + ni * 16 + fr;
            if (col >= N) continue;
            #pragma unroll
            for (int j = 0; j < 4; ++j) {
                int row = m0 + wr * 64 + mi * 16 + fq * 4 + j;
                if (row < M) pbase[(size_t)row * N + col] = acc[mi][ni][j];
            }
        }
    }
}

// ------------------------------- split-K reduce + bias (+relu) -> f32/bf16
__global__ __launch_bounds__(256) void reduce_kernel(
    const float* __restrict__ part, const float* __restrict__ bias,
    float* __restrict__ outf, unsigned short* __restrict__ outh,
    int M, int N, int KS, int relu)
{
    int idx = blockIdx.x * 256 + threadIdx.x;
    int tot = M * N;
    if (idx >= tot) return;
    int n = idx % N;
    float s = 0.f;
    for (int k = 0; k < KS; ++k) s += part[(size_t)k * tot + idx];
    s += bias[n];
    if (relu) s = fmaxf(s, 0.f);
    if (outf) outf[idx] = s;
    if (outh) outh[idx] = f2bf(s);
}

// ------------------------------------- per-row softmax/argmax + reg + decode
__global__ __launch_bounds__(256) void decode_kernel(
    const float* __restrict__ cls, const float* __restrict__ x2buf,
    const float* __restrict__ reg_w, const float* __restrict__ reg_b,
    const float* __restrict__ props,
    float* __restrict__ scores, int* __restrict__ labels,
    float* __restrict__ boxes, int* __restrict__ valid,
    unsigned int* __restrict__ gmax,
    int n0, int rows, const int* __restrict__ img_h, const int* __restrict__ img_w)
{
    int wid = threadIdx.x >> 6, lane = threadIdx.x & 63;
    int rl = blockIdx.x * 4 + wid;
    if (rl >= rows) return;
    int r = n0 + rl;

    float v0 = (lane < NCLS) ? cls[(size_t)r * NCLS + lane] : -INFINITY;
    float v1 = (lane + 64 < NCLS) ? cls[(size_t)r * NCLS + lane + 64] : -INFINITY;

    float mall = fmaxf(v0, v1);
    for (int s = 32; s; s >>= 1) mall = fmaxf(mall, __shfl_xor(mall, s));

    float bv = -INFINITY; int bi = 1 << 30;
    if (lane >= 1 && lane < NCLS) { bv = v0; bi = lane; }
    if (lane + 64 < NCLS && v1 > bv) { bv = v1; bi = lane + 64; }
    for (int s = 32; s; s >>= 1) {
        float ov = __shfl_xor(bv, s); int oi = __shfl_xor(bi, s);
        if (ov > bv || (ov == bv && oi < bi)) { bv = ov; bi = oi; }
    }

    float den = ((lane < NCLS) ? expf(v0 - mall) : 0.f) +
                ((lane + 64 < NCLS) ? expf(v1 - mall) : 0.f);
    for (int s = 32; s; s >>= 1) den += __shfl_xor(den, s);

    float score = expf(bv - mall) / den;
    int label = bi;

    float dsum[4];
    const float* xr = x2buf + (size_t)rl * HID;
    #pragma unroll
    for (int d = 0; d < 4; ++d) {
        const float* wr2 = reg_w + (size_t)(label * 4 + d) * HID;
        float s = 0.f;
        for (int k = lane; k < HID; k += 64) s = fmaf(xr[k], wr2[k], s);
        for (int sh = 32; sh; sh >>= 1) s += __shfl_xor(s, sh);
        dsum[d] = s + reg_b[label * 4 + d];
    }

    if (lane == 0) {
        float p0 = props[r * 4 + 0], p1 = props[r * 4 + 1];
        float p2 = props[r * 4 + 2], p3 = props[r * 4 + 3];
        float pw = p2 - p0, ph = p3 - p1;
        float pcx = p0 + 0.5f * pw, pcy = p1 + 0.5f * ph;
        float dx = dsum[0], dy = dsum[1];
        float dw = fminf(dsum[2], DW_MAXF), dh = fminf(dsum[3], DW_MAXF);
        float cx = dx * pw + pcx, cy = dy * ph + pcy;
        float bw = expf(dw) * pw, bh = expf(dh) * ph;
        float iw = (float)img_w[0], ih = (float)img_h[0];
        float b0 = fminf(fmaxf(cx - 0.5f * bw, 0.f), iw);
        float b1 = fminf(fmaxf(cy - 0.5f * bh, 0.f), ih);
        float b2 = fminf(fmaxf(cx + 0.5f * bw, 0.f), iw);
        float b3 = fminf(fmaxf(cy + 0.5f * bh, 0.f), ih);
        boxes[r * 4 + 0] = b0; boxes[r * 4 + 1] = b1;
        boxes[r * 4 + 2] = b2; boxes[r * 4 + 3] = b3;
        scores[r] = score; labels[r] = label;
        valid[r] = (score >= 0.05f) && (b2 - b0 >= 1.f) && (b3 - b1 >= 1.f);
        atomicMax(gmax, __float_as_uint(b0)); atomicMax(gmax, __float_as_uint(b1));
        atomicMax(gmax, __float_as_uint(b2)); atomicMax(gmax, __float_as_uint(b3));
    }
}

// ---------------------------------------- stable argsort via O(N^2) ranking
__global__ __launch_bounds__(256) void rank_kernel(
    const float* __restrict__ scores, const int* __restrict__ valid,
    int* __restrict__ order, int N)
{
    int i = blockIdx.x * 256 + threadIdx.x;
    __shared__ float sk[256];
    float ki = INFINITY;
    if (i < N && valid[i]) ki = -scores[i];
    int rank = 0;
    for (int j0 = 0; j0 < N; j0 += 256) {
        int j = j0 + threadIdx.x;
        float kj = INFINITY;
        if (j < N && valid[j]) kj = -scores[j];
        __syncthreads();
        sk[threadIdx.x] = kj;
        __syncthreads();
        int lim = min(256, N - j0);
        for (int jj = 0; jj < lim; ++jj) {
            float k2 = sk[jj];
            int jidx = j0 + jj;
            rank += (k2 < ki) || (k2 == ki && jidx < i);
        }
    }
    if (i < N) order[rank] = i;
}

// --------------------------------- gather sorted arrays + offset boxes + vcount
__global__ __launch_bounds__(256) void sortprep_kernel(
    const int* __restrict__ order, const float* __restrict__ boxes,
    const float* __restrict__ scores, const int* __restrict__ labels,
    const int* __restrict__ valid, const unsigned int* __restrict__ gmax,
    float* __restrict__ sob, float* __restrict__ sarea,
    float* __restrict__ sraw, float* __restrict__ ssc, int* __restrict__ slb,
    int* __restrict__ vcount, int N)
{
    int i = blockIdx.x * 256 + threadIdx.x;
    if (i >= N) return;
    int oi = order[i];
    float off = (float)labels[oi] * (__uint_as_float(gmax[0]) + 1.0f);
    float b0 = boxes[oi * 4 + 0] + off, b1 = boxes[oi * 4 + 1] + off;
    float b2 = boxes[oi * 4 + 2] + off, b3 = boxes[oi * 4 + 3] + off;
    sob[i * 4 + 0] = b0; sob[i * 4 + 1] = b1; sob[i * 4 + 2] = b2; sob[i * 4 + 3] = b3;
    sarea[i] = (b2 - b0) * (b3 - b1);
    sraw[i * 4 + 0] = boxes[oi * 4 + 0]; sraw[i * 4 + 1] = boxes[oi * 4 + 1];
    sraw[i * 4 + 2] = boxes[oi * 4 + 2]; sraw[i * 4 + 3] = boxes[oi * 4 + 3];
    ssc[i] = scores[oi]; slb[i] = labels[oi];
    // valid entries form a prefix of the sorted order (key = valid ? -score : +inf)
    if (valid[oi]) atomicAdd(vcount, 1);
}

// --------------------------- IoU>thresh bitmask (j > i), bounded by valid count
__global__ __launch_bounds__(256) void mask_kernel(
    const float* __restrict__ sob, const float* __restrict__ sarea,
    const int* __restrict__ vcount,
    unsigned long long* __restrict__ mask, int N, int NW)
{
    int V = vcount[0];
    int t = threadIdx.x;
    int w = t & 31, il = t >> 5;
    int i = blockIdx.x * 8 + il;
    if (i >= V || w >= NW) return;       // only valid-prefix rows matter
    int jbase = w * 64;
    if (jbase >= V) return;              // suppression bits beyond V never read
    float4 bi = *(const float4*)(sob + (size_t)i * 4);
    float ai = sarea[i];
    unsigned long long bits = 0;
    for (int b = 0; b < 64; ++b) {
        int j = jbase + b;
        if (j > i && j < V) {
            float4 bj = *(const float4*)(sob + (size_t)j * 4);
            float xl = fmaxf(bi.x, bj.x), yt = fmaxf(bi.y, bj.y);
            float xr = fminf(bi.z, bj.z), yb = fminf(bi.w, bj.w);
            float inter = fmaxf(xr - xl, 0.f) * fmaxf(yb - yt, 0.f);
            float iou = inter / (ai + sarea[j] - inter + 1e-9f);
            if (iou > 0.5f) bits |= 1ull << b;
        }
    }
    mask[(size_t)i * NW + w] = bits;
}

// ------------------- serial NMS scan over valid prefix, on-demand row loads
__global__ __launch_bounds__(64) void nms_kernel(
    const unsigned long long* __restrict__ mask,
    const int* __restrict__ vcount,
    const float* __restrict__ sraw, const float* __restrict__ ssc,
    const int* __restrict__ slb, float* __restrict__ out, int N, int NW)
{
    int V = vcount[0];
    int NWv = (V + 63) >> 6;
    int lane = threadIdx.x;
    unsigned long long supp = 0;
    int cnt = 0;
    for (int i = 0; i < V && cnt < TOPK_OUT; ++i) {
        int w = i >> 6, b = i & 63;
        unsigned long long sw = __shfl(supp, w);
        if (!((sw >> b) & 1ull)) {
            // kept: fold in this row's suppression mask (256B, 32 lanes)
            unsigned long long mi =
                (lane < NWv) ? mask[(size_t)i * NW + lane] : 0ull;
            supp |= mi;
            if (lane < 4) out[cnt * 4 + lane] = sraw[i * 4 + lane];
            if (lane == 4) out[4 * TOPK_OUT + cnt] = (float)slb[i];
            if (lane == 5) out[5 * TOPK_OUT + cnt] = ssc[i];
            cnt++;
        }
    }
    for (int s = cnt; s < TOPK_OUT; ++s) {
        if (lane < 4) out[s * 4 + lane] = 0.f;
        if (lane == 4) out[4 * TOPK_OUT + s] = 0.f;
        if (lane == 5) out[5 * TOPK_OUT + s] = 0.f;
    }
}

// --------------------------------------------------------------------------
extern "C" void kernel_launch(void* const* d_in, const int* in_sizes, int n_in,
                              void* d_out, int out_size, void* d_ws, size_t ws_size,
                              hipStream_t stream)
{
    const float* feat  = (const float*)d_in[0];
    const float* props = (const float*)d_in[1];
    const float* fc1_w = (const float*)d_in[2];
    const float* fc1_b = (const float*)d_in[3];
    const float* fc2_w = (const float*)d_in[4];
    const float* fc2_b = (const float*)d_in[5];
    const float* cls_w = (const float*)d_in[6];
    const float* cls_b = (const float*)d_in[7];
    const float* reg_w = (const float*)d_in[8];
    const float* reg_b = (const float*)d_in[9];
    const int* img_h = (const int*)d_in[10];
    const int* img_w = (const int*)d_in[11];
    float* out = (float*)d_out;

    int N = in_sizes[1] / 4;          // 2000
    int NW = (N + 63) >> 6;           // 32
    int n_fc1w = in_sizes[2];         // 12845056
    int n_fc2w = in_sizes[4];         // 1048576
    int n_clsw = in_sizes[6];         // 93184

    auto al = [](size_t x) { return (x + 255) & ~(size_t)255; };

    size_t miscBytes =
        al((size_t)N * NCLS * 4) +                    // cls
        al((size_t)N * 4) * 6 +                       // scores/labels/valid/order/sarea/ssc
        al((size_t)N * 16) * 3 +                      // boxes/sob/sraw
        al((size_t)N * 4) +                           // slb
        al(4) + al(4) +                               // vcount, gmax
        al((size_t)N * NW * 8);                       // mask
    size_t wBytes = al((size_t)n_fc1w * 2) + al((size_t)n_fc2w * 2) +
                    al((size_t)n_clsw * 2);

    size_t partCap = 32u << 20;       // 32 MB
    int chunk = N;
    auto need = [&](int ch, size_t pc) {
        return al(pc) + wBytes + miscBytes +
               al((size_t)ch * DIM * 2) +             // pooled bf16
               al((size_t)ch * HID * 2) +             // x1 bf16
               al((size_t)ch * HID * 4) +             // x2 f32
               al((size_t)ch * HID * 2);              // x2 bf16
    };
    while (need(chunk, partCap) > ws_size && chunk > 125) chunk = (chunk + 1) / 2;
    while (need(chunk, partCap) > ws_size && partCap > ((size_t)chunk * HID * 4 + (4u<<20)))
        partCap >>= 1;

    char* p = (char*)d_ws;
    auto grab = [&](size_t bytes) { char* q = p; p += al(bytes); return q; };
    float* part = (float*)grab(partCap);
    unsigned short* fc1wh = (unsigned short*)grab((size_t)n_fc1w * 2);
    unsigned short* fc2wh = (unsigned short*)grab((size_t)n_fc2w * 2);
    unsigned short* clswh = (unsigned short*)grab((size_t)n_clsw * 2);
    unsigned short* pooledh = (unsigned short*)grab((size_t)chunk * DIM * 2);
    unsigned short* x1h = (unsigned short*)grab((size_t)chunk * HID * 2);
    float* x2f = (float*)grab((size_t)chunk * HID * 4);
    unsigned short* x2h = (unsigned short*)grab((size_t)chunk * HID * 2);
    float* cls    = (float*)grab((size_t)N * NCLS * 4);
    float* scores = (float*)grab((size_t)N * 4);
    int*   labels = (int*)grab((size_t)N * 4);
    int*   valid  = (int*)grab((size_t)N * 4);
    float* boxes  = (float*)grab((size_t)N * 16);
    int*   order  = (int*)grab((size_t)N * 4);
    float* sob    = (float*)grab((size_t)N * 16);
    float* sarea  = (float*)grab((size_t)N * 4);
    float* sraw   = (float*)grab((size_t)N * 16);
    float* ssc    = (float*)grab((size_t)N * 4);
    int*   slb    = (int*)grab((size_t)N * 4);
    int*   vcount = (int*)grab(4);
    unsigned int* gmax = (unsigned int*)grab(4);
    unsigned long long* maskp = (unsigned long long*)grab((size_t)N * NW * 8);

    hipMemsetAsync(vcount, 0, 4, stream);
    hipMemsetAsync(gmax, 0, 4, stream);

    // weight conversions (once per launch)
    wconv_kernel<<<(n_fc1w / 4 + 255) / 256, 256, 0, stream>>>(fc1_w, fc1wh, n_fc1w / 4);
    wconv_kernel<<<(n_fc2w / 4 + 255) / 256, 256, 0, stream>>>(fc2_w, fc2wh, n_fc2w / 4);
    wconv_kernel<<<(n_clsw / 4 + 255) / 256, 256, 0, stream>>>(cls_w, clswh, n_clsw / 4);

    auto gemmb = [&](const unsigned short* Ah, const unsigned short* Bh,
                     const float* bias, float* outf, unsigned short* outh,
                     int M_, int N_, int K_, int relu) {
        int gm = (M_ + GBM - 1) / GBM;
        int gn = (N_ + GBN - 1) / GBN;
        int ksteps = K_ / GBK;
        int KS = 512 / (gm * gn);
        if (KS < 1) KS = 1;
        if (KS > 16) KS = 16;
        long ksMem = (long)(partCap / ((size_t)M_ * N_ * 4));
        if (KS > ksMem) KS = (int)ksMem;
        if (KS > ksteps) KS = ksteps;
        if (KS < 1) KS = 1;
        dim3 g(gn, gm, KS);
        gemm_bf16_kernel<<<g, 256, 0, stream>>>(Ah, Bh, part, M_, N_, K_, ksteps, KS);
        int tot = M_ * N_;
        reduce_kernel<<<(tot + 255) / 256, 256, 0, stream>>>(part, bias, outf, outh,
                                                             M_, N_, KS, relu);
    };

    for (int n0 = 0; n0 < N; n0 += chunk) {
        int rows = min(chunk, N - n0);
        {
            int total = rows * DIM;
            roi_pool_kernel<<<(total + 255) / 256, 256, 0, stream>>>(
                feat, props, pooledh, n0, rows, img_h, img_w);
        }
        gemmb(pooledh, fc1wh, fc1_b, nullptr, x1h, rows, HID, DIM, 1);
        gemmb(x1h, fc2wh, fc2_b, x2f, x2h, rows, HID, HID, 1);
        gemmb(x2h, clswh, cls_b, cls + (size_t)n0 * NCLS, nullptr, rows, NCLS, HID, 0);
        decode_kernel<<<(rows + 3) / 4, 256, 0, stream>>>(
            cls, x2f, reg_w, reg_b, props, scores, labels, boxes, valid,
            gmax, n0, rows, img_h, img_w);
    }

    rank_kernel<<<(N + 255) / 256, 256, 0, stream>>>(scores, valid, order, N);
    sortprep_kernel<<<(N + 255) / 256, 256, 0, stream>>>(
        order, boxes, scores, labels, valid, gmax, sob, sarea, sraw, ssc, slb,
        vcount, N);
    mask_kernel<<<(N + 7) / 8, 256, 0, stream>>>(sob, sarea, vcount, maskp, N, NW);
    nms_kernel<<<1, 64, 0, stream>>>(maskp, vcount, sraw, ssc, slb, out, N, NW);
}